// Round 3
// baseline (311.863 us; speedup 1.0000x reference)
//
#include <hip/hip_runtime.h>
#include <math.h>

#define NLAYER_TOT 12
#define LAYER0 4
#define SMAX 512
#define DIM 768
// B=8, 8 used layers (4..11), T = mask.sum(row0)-1 (511 here)

// packed upper-tri index for 8x8 symmetric gram: rows of length 8,7,6,...
__host__ __device__ constexpr int gp(int i, int j) {
    return (i <= j) ? (i * 8 - i * (i - 1) / 2 + (j - i))
                    : (j * 8 - j * (j - 1) / 2 + (i - j));
}

__device__ inline float frcp(float x) { return __builtin_amdgcn_rcpf(x); }
__device__ inline float frsq(float x) { return __builtin_amdgcn_rsqf(x); }

// ---------------- kernel 0: compute T, zero out + vsum ----------------
__global__ void k_init(const int* __restrict__ mask, int* __restrict__ wsT,
                       float* __restrict__ out, float* __restrict__ vsum) {
    __shared__ int red[512];
    int tid = threadIdx.x;
    red[tid] = mask[tid];  // row 0 of attention_mask
    __syncthreads();
    for (int s = 256; s >= 1; s >>= 1) {
        if (tid < s) red[tid] += red[tid + s];
        __syncthreads();
    }
    if (tid == 0) wsT[0] = red[0] - 1;
    for (int i = tid; i < 8 * DIM; i += 512) out[i] = 0.0f;
    if (tid < 8) vsum[tid] = 0.0f;
}

// ---------------- per-k small math: Cholesky of Gram subset -> align, nov ----------------
// QR's R equals chol(G) up to per-row sign flips; align & nov are invariant to the flips.
template <int W>
__device__ inline void alpha_nov(const float (&A)[36], const int (&idx)[5],
                                 float& align_o, float& nov_o) {
    float Gs[W][W];
#pragma unroll
    for (int i = 0; i < W; ++i)
#pragma unroll
        for (int j = i; j < W; ++j) {
            float v = A[gp(idx[i], idx[j])];
            Gs[i][j] = v;
            Gs[j][i] = v;
        }
    float R[W][W];
#pragma unroll
    for (int j = 0; j < W; ++j) {
#pragma unroll
        for (int i = 0; i <= j; ++i) {
            float s = Gs[i][j];
#pragma unroll
            for (int q = 0; q < i; ++q) s -= R[q][i] * R[q][j];
            if (i == j) R[i][j] = s * frsq(s);       // sqrt(s)
            else        R[i][j] = s * frcp(R[i][i]); // s / R[i][i]
        }
    }
    float ic[W - 1];
#pragma unroll
    for (int j = 0; j < W - 1; ++j) ic[j] = frsq(Gs[j][j]);  // 1/coln[j]
    float m[W - 1];
#pragma unroll
    for (int i = 0; i < W - 1; ++i) {
        float s = 0.0f;
#pragma unroll
        for (int j = i; j < W - 1; ++j) s += R[i][j] * ic[j];
        m[i] = s * (1.0f / (float)(W - 1));
    }
    float num = 0.0f, n1 = 0.0f;
#pragma unroll
    for (int i = 0; i < W - 1; ++i) {
        num += m[i] * R[i][W - 1];
        n1 += R[i][W - 1] * R[i][W - 1];
    }
    float align_raw = num * frsq(n1);
    align_o = frcp(align_raw * (float)W * 2.0f);
    nov_o = fabsf(R[W - 1][W - 1]) * frsq(Gs[W - 1][W - 1]);
}

// ---------------- fused kernel: gram -> alpha/vraw -> unnormalized accumulate ----------------
// One wave per (b,t). out_raw[b,d] += vraw * sum_k alpha_k x[b,k,t,d]; vsum[b] += vraw.
__global__ __launch_bounds__(64) void k_fused(const float* __restrict__ in,
                                              const int* __restrict__ wsT,
                                              float* __restrict__ out,
                                              float* __restrict__ vsum) {
    int T = wsT[0];
    int t = blockIdx.x;
    int b = blockIdx.y;
    if (t >= T) return;
    int lane = threadIdx.x;
    const float* base = in + ((size_t)(b * NLAYER_TOT + LAYER0) * SMAX + t) * DIM;

    // --- gram accumulate ---
    float acc[36];
#pragma unroll
    for (int p = 0; p < 36; ++p) acc[p] = 0.0f;
#pragma unroll
    for (int it = 0; it < 3; ++it) {
        int d = it * 256 + lane * 4;
        float4 x[8];
#pragma unroll
        for (int k = 0; k < 8; ++k)
            x[k] = *(const float4*)(base + (size_t)k * SMAX * DIM + d);
        int p = 0;
#pragma unroll
        for (int i = 0; i < 8; ++i)
#pragma unroll
            for (int j = i; j < 8; ++j) {
                acc[p] += x[i].x * x[j].x + x[i].y * x[j].y + x[i].z * x[j].z + x[i].w * x[j].w;
                ++p;
            }
    }
    // butterfly full-reduce: every lane ends with the complete sums
#pragma unroll
    for (int p = 0; p < 36; ++p) {
#pragma unroll
        for (int off = 32; off >= 1; off >>= 1) acc[p] += __shfl_xor(acc[p], off, 64);
    }

    // --- alpha (all lanes redundant; values identical) ---
    // Reference: left window only when k >= WS(=2); right = k+1..min(k+2,7); then k last.
    static constexpr int IDX0[5] = {1, 2, 0, 0, 0};
    static constexpr int IDX1[5] = {2, 3, 1, 0, 0};
    static constexpr int IDX2[5] = {0, 1, 3, 4, 2};
    static constexpr int IDX3[5] = {1, 2, 4, 5, 3};
    static constexpr int IDX4[5] = {2, 3, 5, 6, 4};
    static constexpr int IDX5[5] = {3, 4, 6, 7, 5};
    static constexpr int IDX6[5] = {4, 5, 7, 6, 0};
    static constexpr int IDX7[5] = {5, 6, 7, 0, 0};
    float a[8], n[8];
    alpha_nov<3>(acc, IDX0, a[0], n[0]);
    alpha_nov<3>(acc, IDX1, a[1], n[1]);
    alpha_nov<5>(acc, IDX2, a[2], n[2]);
    alpha_nov<5>(acc, IDX3, a[3], n[3]);
    alpha_nov<5>(acc, IDX4, a[4], n[4]);
    alpha_nov<5>(acc, IDX5, a[5], n[5]);
    alpha_nov<4>(acc, IDX6, a[6], n[6]);
    alpha_nov<3>(acc, IDX7, a[7], n[7]);
    float sa = 0.0f, sn = 0.0f;
#pragma unroll
    for (int k = 0; k < 8; ++k) { sa += a[k]; sn += n[k]; }
    float isa = frcp(sa), isn = frcp(sn);
    float al[8], ss = 0.0f;
#pragma unroll
    for (int k = 0; k < 8; ++k) { al[k] = a[k] * isa + n[k] * isn; ss += al[k]; }
    float iss = frcp(ss);

    // --- token variance (consecutive-layer cosine sims) ---
    float c[7], mu = 0.0f;
#pragma unroll
    for (int i = 0; i < 7; ++i) {
        float denom = acc[gp(i, i)] * acc[gp(i + 1, i + 1)];
        c[i] = acc[gp(i, i + 1)] * frsq(denom > 1e-16f ? denom : 1e-16f);
        mu += c[i];
    }
    mu *= (1.0f / 7.0f);
    float var = 0.0f;
#pragma unroll
    for (int i = 0; i < 7; ++i) var += (c[i] - mu) * (c[i] - mu);
    float vraw = var * (1.0f / 6.0f);  // ddof=1

    if (lane == 0) atomicAdd(&vsum[b], vraw);

    // --- weighted accumulate: p_k = vraw * alpha_k; reload x (cache-hot) ---
    float p8[8];
#pragma unroll
    for (int k = 0; k < 8; ++k) p8[k] = al[k] * iss * vraw;
    float* od = out + (size_t)b * DIM;
#pragma unroll
    for (int it = 0; it < 3; ++it) {
        int d = it * 256 + lane * 4;
        float4 s = make_float4(0.f, 0.f, 0.f, 0.f);
#pragma unroll
        for (int k = 0; k < 8; ++k) {
            float4 x = *(const float4*)(base + (size_t)k * SMAX * DIM + d);
            s.x += p8[k] * x.x; s.y += p8[k] * x.y;
            s.z += p8[k] * x.z; s.w += p8[k] * x.w;
        }
        atomicAdd(&od[d + 0], s.x);
        atomicAdd(&od[d + 1], s.y);
        atomicAdd(&od[d + 2], s.z);
        atomicAdd(&od[d + 3], s.w);
    }
}

// ---------------- final scale: out[b,:] /= vsum[b] ----------------
__global__ void k_scale(float* __restrict__ out, const float* __restrict__ vsum) {
    int i = blockIdx.x * blockDim.x + threadIdx.x;
    if (i >= 8 * DIM) return;
    int b = i / DIM;
    out[i] = out[i] / vsum[b];
}

extern "C" void kernel_launch(void* const* d_in, const int* in_sizes, int n_in,
                              void* d_out, int out_size, void* d_ws, size_t ws_size,
                              hipStream_t stream) {
    const float* hs = (const float*)d_in[0];   // (8, 12, 512, 768) f32
    const int* mask = (const int*)d_in[1];     // (8, 512) i32
    float* out = (float*)d_out;                // (8, 768) f32
    char* ws = (char*)d_ws;
    int* wsT = (int*)ws;                       // [0] T
    float* vsum = (float*)(ws + 256);          // 8 floats

    k_init<<<1, 512, 0, stream>>>(mask, wsT, out, vsum);
    k_fused<<<dim3(SMAX - 1, 8), 64, 0, stream>>>(hs, wsT, out, vsum);
    k_scale<<<(8 * DIM + 255) / 256, 256, 0, stream>>>(out, vsum);
}

// Round 4
// 246.342 us; speedup vs baseline: 1.2660x; 1.2660x over previous
//
#include <hip/hip_runtime.h>
#include <math.h>

#define NLAYER_TOT 12
#define LAYER0 4
#define SMAX 512
#define DIM 768
// B=8, 8 used layers (4..11), T = mask.sum(row0)-1 (511 here)

// packed upper-tri index for 8x8 symmetric gram
__host__ __device__ constexpr int gp(int i, int j) {
    return (i <= j) ? (i * 8 - i * (i - 1) / 2 + (j - i))
                    : (j * 8 - j * (j - 1) / 2 + (i - j));
}

__device__ inline float frcp(float x) { return __builtin_amdgcn_rcpf(x); }
__device__ inline float frsq(float x) { return __builtin_amdgcn_rsqf(x); }

// ---------------- kernel 0: compute T, zero out ----------------
__global__ void k_init(const int* __restrict__ mask, int* __restrict__ wsT,
                       float* __restrict__ out) {
    __shared__ int red[512];
    int tid = threadIdx.x;
    red[tid] = mask[tid];  // row 0 of attention_mask
    __syncthreads();
    for (int s = 256; s >= 1; s >>= 1) {
        if (tid < s) red[tid] += red[tid + s];
        __syncthreads();
    }
    if (tid == 0) wsT[0] = red[0] - 1;
    for (int i = tid; i < 8 * DIM; i += 512) out[i] = 0.0f;
}

// ---------------- kernel 1: per-(b,t) 8x8 Gram, 4 tokens per 256-thr block ----------------
__global__ __launch_bounds__(256) void k_gram(const float* __restrict__ in,
                                              const int* __restrict__ wsT,
                                              float* __restrict__ Gout) {
    int T = wsT[0];
    int wave = threadIdx.x >> 6;
    int lane = threadIdx.x & 63;
    int t = blockIdx.x * 4 + wave;
    int b = blockIdx.y;
    if (t >= T) return;
    const float* base = in + ((size_t)(b * NLAYER_TOT + LAYER0) * SMAX + t) * DIM;
    float acc[36];
#pragma unroll
    for (int p = 0; p < 36; ++p) acc[p] = 0.0f;

    float4 cur[8], nxt[8];
#pragma unroll
    for (int k = 0; k < 8; ++k)
        cur[k] = *(const float4*)(base + (size_t)k * SMAX * DIM + lane * 4);
#pragma unroll
    for (int it = 0; it < 3; ++it) {
        if (it < 2) {
            int d = (it + 1) * 256 + lane * 4;
#pragma unroll
            for (int k = 0; k < 8; ++k)
                nxt[k] = *(const float4*)(base + (size_t)k * SMAX * DIM + d);
        }
        int p = 0;
#pragma unroll
        for (int i = 0; i < 8; ++i)
#pragma unroll
            for (int j = i; j < 8; ++j) {
                acc[p] += cur[i].x * cur[j].x + cur[i].y * cur[j].y +
                          cur[i].z * cur[j].z + cur[i].w * cur[j].w;
                ++p;
            }
        if (it < 2) {
#pragma unroll
            for (int k = 0; k < 8; ++k) cur[k] = nxt[k];
        }
    }
    float* gdst = Gout + ((size_t)b * SMAX + t) * 36;
#pragma unroll
    for (int p = 0; p < 36; ++p) {
        float v = acc[p];
#pragma unroll
        for (int off = 32; off >= 1; off >>= 1) v += __shfl_xor(v, off, 64);
        if (lane == 0) gdst[p] = v;
    }
}

// ---------------- per-k small math: Cholesky of Gram subset -> align, nov ----------------
// QR's R equals chol(G) up to per-row sign flips; align & nov are invariant to the flips.
template <int W>
__device__ inline void alpha_nov(const float (&A)[36], const int (&idx)[5],
                                 float& align_o, float& nov_o) {
    float Gs[W][W];
#pragma unroll
    for (int i = 0; i < W; ++i)
#pragma unroll
        for (int j = i; j < W; ++j) {
            float v = A[gp(idx[i], idx[j])];
            Gs[i][j] = v;
            Gs[j][i] = v;
        }
    float R[W][W];
#pragma unroll
    for (int j = 0; j < W; ++j) {
#pragma unroll
        for (int i = 0; i <= j; ++i) {
            float s = Gs[i][j];
#pragma unroll
            for (int q = 0; q < i; ++q) s -= R[q][i] * R[q][j];
            if (i == j) R[i][j] = s * frsq(s);       // sqrt(s)
            else        R[i][j] = s * frcp(R[i][i]); // s / R[i][i]
        }
    }
    float ic[W - 1];
#pragma unroll
    for (int j = 0; j < W - 1; ++j) ic[j] = frsq(Gs[j][j]);  // 1/coln[j]
    float m[W - 1];
#pragma unroll
    for (int i = 0; i < W - 1; ++i) {
        float s = 0.0f;
#pragma unroll
        for (int j = i; j < W - 1; ++j) s += R[i][j] * ic[j];
        m[i] = s * (1.0f / (float)(W - 1));
    }
    float num = 0.0f, n1 = 0.0f;
#pragma unroll
    for (int i = 0; i < W - 1; ++i) {
        num += m[i] * R[i][W - 1];
        n1 += R[i][W - 1] * R[i][W - 1];
    }
    float align_raw = num * frsq(n1);
    align_o = frcp(align_raw * (float)W * 2.0f);
    nov_o = fabsf(R[W - 1][W - 1]) * frsq(Gs[W - 1][W - 1]);
}

// ---------------- kernel 2: per-token alpha (normalized) + raw variance ----------------
__global__ __launch_bounds__(64) void k_alpha(const int* __restrict__ wsT,
                                              const float* __restrict__ Gin,
                                              float* __restrict__ alpha,
                                              float* __restrict__ vraw) {
    int T = wsT[0];
    int id = blockIdx.x * 64 + threadIdx.x;
    int b = id >> 9;
    int t = id & 511;
    if (b >= 8 || t >= T) return;
    float A[36];
    const float* gsrc = Gin + ((size_t)b * SMAX + t) * 36;
#pragma unroll
    for (int p = 0; p < 36; ++p) A[p] = gsrc[p];
    // Reference: left window only when k >= WS(=2); right = k+1..min(k+2,7); then k last.
    static constexpr int IDX0[5] = {1, 2, 0, 0, 0};
    static constexpr int IDX1[5] = {2, 3, 1, 0, 0};
    static constexpr int IDX2[5] = {0, 1, 3, 4, 2};
    static constexpr int IDX3[5] = {1, 2, 4, 5, 3};
    static constexpr int IDX4[5] = {2, 3, 5, 6, 4};
    static constexpr int IDX5[5] = {3, 4, 6, 7, 5};
    static constexpr int IDX6[5] = {4, 5, 7, 6, 0};
    static constexpr int IDX7[5] = {5, 6, 7, 0, 0};
    float a[8], n[8];
    alpha_nov<3>(A, IDX0, a[0], n[0]);
    alpha_nov<3>(A, IDX1, a[1], n[1]);
    alpha_nov<5>(A, IDX2, a[2], n[2]);
    alpha_nov<5>(A, IDX3, a[3], n[3]);
    alpha_nov<5>(A, IDX4, a[4], n[4]);
    alpha_nov<5>(A, IDX5, a[5], n[5]);
    alpha_nov<4>(A, IDX6, a[6], n[6]);
    alpha_nov<3>(A, IDX7, a[7], n[7]);
    float sa = 0.0f, sn = 0.0f;
#pragma unroll
    for (int k = 0; k < 8; ++k) { sa += a[k]; sn += n[k]; }
    float isa = frcp(sa), isn = frcp(sn);
    float al[8], ss = 0.0f;
#pragma unroll
    for (int k = 0; k < 8; ++k) { al[k] = a[k] * isa + n[k] * isn; ss += al[k]; }
    float iss = frcp(ss);
    float* adst = alpha + ((size_t)b * SMAX + t) * 8;
#pragma unroll
    for (int k = 0; k < 8; ++k) adst[k] = al[k] * iss;
    // token variance: consecutive-layer cosine sims
    float c[7], mu = 0.0f;
#pragma unroll
    for (int i = 0; i < 7; ++i) {
        float denom = A[gp(i, i)] * A[gp(i + 1, i + 1)];
        c[i] = A[gp(i, i + 1)] * frsq(denom > 1e-16f ? denom : 1e-16f);
        mu += c[i];
    }
    mu *= (1.0f / 7.0f);
    float var = 0.0f;
#pragma unroll
    for (int i = 0; i < 7; ++i) var += (c[i] - mu) * (c[i] - mu);
    vraw[(size_t)b * SMAX + t] = var * (1.0f / 6.0f);  // ddof=1
}

// ---------------- kernel 3: per-sentence v normalization, fold into W[b,t,k] ----------------
__global__ void k_weights(const int* __restrict__ wsT, const float* __restrict__ alpha,
                          const float* __restrict__ vraw, float* __restrict__ W) {
    int T = wsT[0];
    int b = blockIdx.x;
    int tid = threadIdx.x;
    __shared__ float red[256];
    float s = 0.0f;
    for (int t = tid; t < T; t += 256) s += vraw[(size_t)b * SMAX + t];
    red[tid] = s;
    __syncthreads();
    for (int k = 128; k >= 1; k >>= 1) {
        if (tid < k) red[tid] += red[tid + k];
        __syncthreads();
    }
    float inv = frcp(red[0]);
    for (int t = tid; t < T; t += 256) {
        float v = vraw[(size_t)b * SMAX + t] * inv;
#pragma unroll
        for (int k = 0; k < 8; ++k)
            W[((size_t)b * SMAX + t) * 8 + k] = alpha[((size_t)b * SMAX + t) * 8 + k] * v;
    }
}

// ---------------- kernel 4: out[b,d] = sum_{t,k} W[b,t,k] * sf[b,k,t,d] ----------------
__global__ void k_out(const float* __restrict__ in, const int* __restrict__ wsT,
                      const float* __restrict__ W, float* __restrict__ out) {
    int T = wsT[0];
    int tseg = blockIdx.x;   // 0..31, 16 tokens each
    int dchunk = blockIdx.y; // 0..2
    int b = blockIdx.z;      // 0..7
    int d = dchunk * 256 + threadIdx.x;
    int t0 = tseg * 16;
    int t1 = min(t0 + 16, T);
    if (t0 >= t1) return;
    const float* base = in + ((size_t)(b * NLAYER_TOT + LAYER0) * SMAX) * DIM + d;
    const float* wb = W + (size_t)b * SMAX * 8;
    float acc0 = 0.0f, acc1 = 0.0f;
    int t = t0;
    for (; t + 1 < t1; t += 2) {  // 2-token unroll: 16 independent loads in flight
#pragma unroll
        for (int k = 0; k < 8; ++k) {
            acc0 += wb[t * 8 + k] * base[((size_t)k * SMAX + t) * DIM];
            acc1 += wb[(t + 1) * 8 + k] * base[((size_t)k * SMAX + t + 1) * DIM];
        }
    }
    if (t < t1) {
#pragma unroll
        for (int k = 0; k < 8; ++k)
            acc0 += wb[t * 8 + k] * base[((size_t)k * SMAX + t) * DIM];
    }
    atomicAdd(&out[b * DIM + d], acc0 + acc1);
}

extern "C" void kernel_launch(void* const* d_in, const int* in_sizes, int n_in,
                              void* d_out, int out_size, void* d_ws, size_t ws_size,
                              hipStream_t stream) {
    const float* hs = (const float*)d_in[0];   // (8, 12, 512, 768) f32
    const int* mask = (const int*)d_in[1];     // (8, 512) i32
    float* out = (float*)d_out;                // (8, 768) f32
    char* ws = (char*)d_ws;
    // ws layout: [0] int T | [256] G 8*512*36 f | alpha 8*512*8 f | vraw 8*512 f | W 8*512*8 f
    int* wsT = (int*)ws;
    float* G = (float*)(ws + 256);
    float* alpha = (float*)(ws + 256 + (size_t)8 * 512 * 36 * 4);
    float* vraw = (float*)(ws + 256 + (size_t)(8 * 512 * 36 + 8 * 512 * 8) * 4);
    float* W = (float*)(ws + 256 + (size_t)(8 * 512 * 36 + 8 * 512 * 8 + 8 * 512) * 4);

    k_init<<<1, 512, 0, stream>>>(mask, wsT, out);
    k_gram<<<dim3(128, 8), 256, 0, stream>>>(hs, wsT, G);
    k_alpha<<<64, 64, 0, stream>>>(wsT, G, alpha, vraw);
    k_weights<<<8, 256, 0, stream>>>(wsT, alpha, vraw, W);
    k_out<<<dim3(32, 3, 8), 256, 0, stream>>>(hs, wsT, W, out);
}

// Round 5
// 232.913 us; speedup vs baseline: 1.3390x; 1.0577x over previous
//
#include <hip/hip_runtime.h>
#include <math.h>

#define NLAYER_TOT 12
#define LAYER0 4
#define SMAX 512
#define DIM 768
#define NSEG 64   // token segments; 8 tokens per segment, 64*8=512 >= T
// B=8, 8 used layers (4..11), T = mask.sum(row0)-1 (511 here)

// packed upper-tri index for 8x8 symmetric gram
__host__ __device__ constexpr int gp(int i, int j) {
    return (i <= j) ? (i * 8 - i * (i - 1) / 2 + (j - i))
                    : (j * 8 - j * (j - 1) / 2 + (i - j));
}

__device__ inline float frcp(float x) { return __builtin_amdgcn_rcpf(x); }
__device__ inline float frsq(float x) { return __builtin_amdgcn_rsqf(x); }

// ---------------- kernel 0: compute T ----------------
__global__ void k_init(const int* __restrict__ mask, int* __restrict__ wsT) {
    __shared__ int red[512];
    int tid = threadIdx.x;
    red[tid] = mask[tid];  // row 0 of attention_mask
    __syncthreads();
    for (int s = 256; s >= 1; s >>= 1) {
        if (tid < s) red[tid] += red[tid + s];
        __syncthreads();
    }
    if (tid == 0) wsT[0] = red[0] - 1;
}

// ---------------- per-k small math: Cholesky of Gram subset -> align, nov ----------------
// QR's R equals chol(G) up to per-row sign flips; align & nov are invariant to the flips.
template <int W>
__device__ inline void alpha_nov(const float (&A)[36], const int (&idx)[5],
                                 float& align_o, float& nov_o) {
    float Gs[W][W];
#pragma unroll
    for (int i = 0; i < W; ++i)
#pragma unroll
        for (int j = i; j < W; ++j) {
            float v = A[gp(idx[i], idx[j])];
            Gs[i][j] = v;
            Gs[j][i] = v;
        }
    float R[W][W];
#pragma unroll
    for (int j = 0; j < W; ++j) {
#pragma unroll
        for (int i = 0; i <= j; ++i) {
            float s = Gs[i][j];
#pragma unroll
            for (int q = 0; q < i; ++q) s -= R[q][i] * R[q][j];
            if (i == j) R[i][j] = s * frsq(s);       // sqrt(s)
            else        R[i][j] = s * frcp(R[i][i]); // s / R[i][i]
        }
    }
    float ic[W - 1];
#pragma unroll
    for (int j = 0; j < W - 1; ++j) ic[j] = frsq(Gs[j][j]);  // 1/coln[j]
    float m[W - 1];
#pragma unroll
    for (int i = 0; i < W - 1; ++i) {
        float s = 0.0f;
#pragma unroll
        for (int j = i; j < W - 1; ++j) s += R[i][j] * ic[j];
        m[i] = s * (1.0f / (float)(W - 1));
    }
    float num = 0.0f, n1 = 0.0f;
#pragma unroll
    for (int i = 0; i < W - 1; ++i) {
        num += m[i] * R[i][W - 1];
        n1 += R[i][W - 1] * R[i][W - 1];
    }
    float align_raw = num * frsq(n1);
    align_o = frcp(align_raw * (float)W * 2.0f);
    nov_o = fabsf(R[W - 1][W - 1]) * frsq(Gs[W - 1][W - 1]);
}

// ---------------- main single-pass kernel ----------------
// Block = 256 thr (4 waves), handles 8 tokens of one (b, seg): wave w -> tokens seg*8+w*2+{0,1}.
// Each wave: load token slice (8x768) into regs once; gram via butterfly; alpha/vraw
// lane-redundant; weighted accumulate in regs. Block-level LDS reduce -> partial vector.
// No global atomics anywhere.
__global__ __launch_bounds__(256, 2) void k_main(const float* __restrict__ in,
                                                 const int* __restrict__ wsT,
                                                 float* __restrict__ P,    // [8][NSEG][768]
                                                 float* __restrict__ Vp) { // [8][NSEG]
    int T = wsT[0];
    int seg = blockIdx.x;  // 0..NSEG-1
    int b = blockIdx.y;    // 0..7
    int wave = threadIdx.x >> 6;
    int lane = threadIdx.x & 63;

    __shared__ float part[DIM];
    __shared__ float vpart;
    for (int i = threadIdx.x; i < DIM; i += 256) part[i] = 0.0f;
    if (threadIdx.x == 0) vpart = 0.0f;
    __syncthreads();

    const float* bbase = in + (size_t)(b * NLAYER_TOT + LAYER0) * SMAX * DIM;

    float4 acc12[3];
#pragma unroll
    for (int it = 0; it < 3; ++it) acc12[it] = make_float4(0.f, 0.f, 0.f, 0.f);
    float vloc = 0.0f;

    // Reference window tables: left only when k >= WS(=2); right = k+1..min(k+2,7); k last.
    static constexpr int IDX0[5] = {1, 2, 0, 0, 0};
    static constexpr int IDX1[5] = {2, 3, 1, 0, 0};
    static constexpr int IDX2[5] = {0, 1, 3, 4, 2};
    static constexpr int IDX3[5] = {1, 2, 4, 5, 3};
    static constexpr int IDX4[5] = {2, 3, 5, 6, 4};
    static constexpr int IDX5[5] = {3, 4, 6, 7, 5};
    static constexpr int IDX6[5] = {4, 5, 7, 6, 0};
    static constexpr int IDX7[5] = {5, 6, 7, 0, 0};

#pragma unroll
    for (int ti = 0; ti < 2; ++ti) {
        int t = seg * 8 + wave * 2 + ti;
        if (t >= T) continue;
        const float* base = bbase + (size_t)t * DIM;
        // load the whole token slice into registers: 8 layers x 3 float4
        float4 x[8][3];
#pragma unroll
        for (int k = 0; k < 8; ++k)
#pragma unroll
            for (int it = 0; it < 3; ++it)
                x[k][it] = *(const float4*)(base + (size_t)k * SMAX * DIM + it * 256 + lane * 4);
        // gram partials
        float g[36];
#pragma unroll
        for (int p = 0; p < 36; ++p) g[p] = 0.0f;
#pragma unroll
        for (int it = 0; it < 3; ++it) {
            int p = 0;
#pragma unroll
            for (int i = 0; i < 8; ++i)
#pragma unroll
                for (int j = i; j < 8; ++j) {
                    g[p] += x[i][it].x * x[j][it].x + x[i][it].y * x[j][it].y +
                            x[i][it].z * x[j][it].z + x[i][it].w * x[j][it].w;
                    ++p;
                }
        }
        // butterfly full-reduce (all lanes get full sums)
#pragma unroll
        for (int p = 0; p < 36; ++p) {
#pragma unroll
            for (int off = 32; off >= 1; off >>= 1) g[p] += __shfl_xor(g[p], off, 64);
        }
        // alpha (lane-redundant)
        float a[8], n[8];
        alpha_nov<3>(g, IDX0, a[0], n[0]);
        alpha_nov<3>(g, IDX1, a[1], n[1]);
        alpha_nov<5>(g, IDX2, a[2], n[2]);
        alpha_nov<5>(g, IDX3, a[3], n[3]);
        alpha_nov<5>(g, IDX4, a[4], n[4]);
        alpha_nov<5>(g, IDX5, a[5], n[5]);
        alpha_nov<4>(g, IDX6, a[6], n[6]);
        alpha_nov<3>(g, IDX7, a[7], n[7]);
        float sa = 0.0f, sn = 0.0f;
#pragma unroll
        for (int k = 0; k < 8; ++k) { sa += a[k]; sn += n[k]; }
        float isa = frcp(sa), isn = frcp(sn);
        float al[8], ss = 0.0f;
#pragma unroll
        for (int k = 0; k < 8; ++k) { al[k] = a[k] * isa + n[k] * isn; ss += al[k]; }
        float iss = frcp(ss);
        // token variance (consecutive-layer cosine sims)
        float c[7], mu = 0.0f;
#pragma unroll
        for (int i = 0; i < 7; ++i) {
            float denom = g[gp(i, i)] * g[gp(i + 1, i + 1)];
            c[i] = g[gp(i, i + 1)] * frsq(denom > 1e-16f ? denom : 1e-16f);
            mu += c[i];
        }
        mu *= (1.0f / 7.0f);
        float var = 0.0f;
#pragma unroll
        for (int i = 0; i < 7; ++i) var += (c[i] - mu) * (c[i] - mu);
        float vraw = var * (1.0f / 6.0f);  // ddof=1
        vloc += vraw;
        // weighted accumulate into register accumulator (x is already in regs!)
        float p8[8];
#pragma unroll
        for (int k = 0; k < 8; ++k) p8[k] = al[k] * iss * vraw;
#pragma unroll
        for (int it = 0; it < 3; ++it) {
#pragma unroll
            for (int k = 0; k < 8; ++k) {
                acc12[it].x += p8[k] * x[k][it].x;
                acc12[it].y += p8[k] * x[k][it].y;
                acc12[it].z += p8[k] * x[k][it].z;
                acc12[it].w += p8[k] * x[k][it].w;
            }
        }
    }

    // block-level reduce: 4 waves -> shared part[] (max 4-way conflict per address)
#pragma unroll
    for (int it = 0; it < 3; ++it) {
        int d = it * 256 + lane * 4;
        atomicAdd(&part[d + 0], acc12[it].x);
        atomicAdd(&part[d + 1], acc12[it].y);
        atomicAdd(&part[d + 2], acc12[it].z);
        atomicAdd(&part[d + 3], acc12[it].w);
    }
    if (lane == 0) atomicAdd(&vpart, vloc);
    __syncthreads();

    float* pd = P + ((size_t)b * NSEG + seg) * DIM;
    for (int i = threadIdx.x; i < DIM; i += 256) pd[i] = part[i];
    if (threadIdx.x == 0) Vp[b * NSEG + seg] = vpart;
}

// ---------------- final reduce: out[b,d] = sum_seg P / sum_seg Vp ----------------
__global__ void k_reduce(const float* __restrict__ P, const float* __restrict__ Vp,
                         float* __restrict__ out) {
    int b = blockIdx.x;
    int d = threadIdx.x;  // 768 threads
    __shared__ float vred[64];
    __shared__ float vinv;
    if (d < 64) vred[d] = Vp[b * NSEG + d];
    __syncthreads();
    if (d == 0) {
        float s = 0.0f;
        for (int i = 0; i < 64; ++i) s += vred[i];
        vinv = 1.0f / s;
    }
    __syncthreads();
    float s = 0.0f;
    const float* pb = P + (size_t)b * NSEG * DIM;
    for (int seg = 0; seg < NSEG; ++seg) s += pb[(size_t)seg * DIM + d];
    out[b * DIM + d] = s * vinv;
}

extern "C" void kernel_launch(void* const* d_in, const int* in_sizes, int n_in,
                              void* d_out, int out_size, void* d_ws, size_t ws_size,
                              hipStream_t stream) {
    const float* hs = (const float*)d_in[0];   // (8, 12, 512, 768) f32
    const int* mask = (const int*)d_in[1];     // (8, 512) i32
    float* out = (float*)d_out;                // (8, 768) f32
    char* ws = (char*)d_ws;
    // ws layout: [0] int T | [256] P 8*64*768 f | Vp 8*64 f
    int* wsT = (int*)ws;
    float* P = (float*)(ws + 256);
    float* Vp = (float*)(ws + 256 + (size_t)8 * NSEG * DIM * 4);

    k_init<<<1, 512, 0, stream>>>(mask, wsT);
    k_main<<<dim3(NSEG, 8), 256, 0, stream>>>(hs, wsT, P, Vp);
    k_reduce<<<8, DIM, 0, stream>>>(P, Vp, out);
}

// Round 6
// 224.131 us; speedup vs baseline: 1.3914x; 1.0392x over previous
//
#include <hip/hip_runtime.h>
#include <math.h>

#define NLAYER_TOT 12
#define LAYER0 4
#define SMAX 512
#define DIM 768
#define NSEG 128  // 4 tokens per segment, 128*4=512 >= T
// B=8, 8 used layers (4..11), T = mask.sum(row0)-1 (511 here)

// packed upper-tri index for 8x8 symmetric gram
__host__ __device__ constexpr int gp(int i, int j) {
    return (i <= j) ? (i * 8 - i * (i - 1) / 2 + (j - i))
                    : (j * 8 - j * (j - 1) / 2 + (i - j));
}

__device__ inline float frcp(float x) { return __builtin_amdgcn_rcpf(x); }
__device__ inline float frsq(float x) { return __builtin_amdgcn_rsqf(x); }

// wave64 reduce-to-all: 4 DPP row_ror adds (VALU rate) + 2 cross-row shuffles (DS)
__device__ inline float wave_reduce_add(float v) {
    v += __int_as_float(__builtin_amdgcn_update_dpp(0, __float_as_int(v), 0x121, 0xF, 0xF, true));
    v += __int_as_float(__builtin_amdgcn_update_dpp(0, __float_as_int(v), 0x122, 0xF, 0xF, true));
    v += __int_as_float(__builtin_amdgcn_update_dpp(0, __float_as_int(v), 0x124, 0xF, 0xF, true));
    v += __int_as_float(__builtin_amdgcn_update_dpp(0, __float_as_int(v), 0x128, 0xF, 0xF, true));
    v += __shfl_xor(v, 16, 64);
    v += __shfl_xor(v, 32, 64);
    return v;
}

// ---------------- kernel 0: compute T ----------------
__global__ void k_init(const int* __restrict__ mask, int* __restrict__ wsT) {
    __shared__ int red[512];
    int tid = threadIdx.x;
    red[tid] = mask[tid];  // row 0 of attention_mask
    __syncthreads();
    for (int s = 256; s >= 1; s >>= 1) {
        if (tid < s) red[tid] += red[tid + s];
        __syncthreads();
    }
    if (tid == 0) wsT[0] = red[0] - 1;
}

// ---------------- per-k small math: Cholesky of Gram subset -> align, nov ----------------
// QR's R equals chol(G) up to per-row sign flips; align & nov are invariant to the flips.
template <int W>
__device__ inline void alpha_nov(const float (&A)[36], const int (&idx)[5],
                                 float& align_o, float& nov_o) {
    float Gs[W][W];
#pragma unroll
    for (int i = 0; i < W; ++i)
#pragma unroll
        for (int j = i; j < W; ++j) {
            float v = A[gp(idx[i], idx[j])];
            Gs[i][j] = v;
            Gs[j][i] = v;
        }
    float R[W][W];
#pragma unroll
    for (int j = 0; j < W; ++j) {
#pragma unroll
        for (int i = 0; i <= j; ++i) {
            float s = Gs[i][j];
#pragma unroll
            for (int q = 0; q < i; ++q) s -= R[q][i] * R[q][j];
            if (i == j) R[i][j] = s * frsq(s);       // sqrt(s)
            else        R[i][j] = s * frcp(R[i][i]); // s / R[i][i]
        }
    }
    float ic[W - 1];
#pragma unroll
    for (int j = 0; j < W - 1; ++j) ic[j] = frsq(Gs[j][j]);  // 1/coln[j]
    float m[W - 1];
#pragma unroll
    for (int i = 0; i < W - 1; ++i) {
        float s = 0.0f;
#pragma unroll
        for (int j = i; j < W - 1; ++j) s += R[i][j] * ic[j];
        m[i] = s * (1.0f / (float)(W - 1));
    }
    float num = 0.0f, n1 = 0.0f;
#pragma unroll
    for (int i = 0; i < W - 1; ++i) {
        num += m[i] * R[i][W - 1];
        n1 += R[i][W - 1] * R[i][W - 1];
    }
    float align_raw = num * frsq(n1);
    align_o = frcp(align_raw * (float)W * 2.0f);
    nov_o = fabsf(R[W - 1][W - 1]) * frsq(Gs[W - 1][W - 1]);
}

// ---------------- main single-pass kernel ----------------
// Block = 256 thr (4 waves); wave w handles token seg*4+w. Gram pass streams from HBM
// (registers NOT held); chol lane-redundant while L2-hot reload chunk is in flight;
// weighted accumulate re-reads from L2. Block LDS reduce -> per-(b,seg) partials.
__global__ __launch_bounds__(256, 2) void k_main(const float* __restrict__ in,
                                                 const int* __restrict__ wsT,
                                                 float* __restrict__ P,    // [8][NSEG][768]
                                                 float* __restrict__ Vp) { // [8][NSEG]
    int T = wsT[0];
    int seg = blockIdx.x;  // 0..NSEG-1
    int b = blockIdx.y;    // 0..7
    int wave = threadIdx.x >> 6;
    int lane = threadIdx.x & 63;

    __shared__ float part[DIM];
    __shared__ float vpart;
    for (int i = threadIdx.x; i < DIM; i += 256) part[i] = 0.0f;
    if (threadIdx.x == 0) vpart = 0.0f;
    __syncthreads();

    int t = seg * 4 + wave;
    float4 acc12[3];
#pragma unroll
    for (int it = 0; it < 3; ++it) acc12[it] = make_float4(0.f, 0.f, 0.f, 0.f);
    float vloc = 0.0f;

    if (t < T) {
        const float* base = in + ((size_t)(b * NLAYER_TOT + LAYER0) * SMAX + t) * DIM;

        // --- Phase A: gram with prefetch; x not held past use ---
        float g[36];
#pragma unroll
        for (int p = 0; p < 36; ++p) g[p] = 0.0f;
        float4 cur[8], nxt[8];
#pragma unroll
        for (int k = 0; k < 8; ++k)
            cur[k] = *(const float4*)(base + (size_t)k * SMAX * DIM + lane * 4);
#pragma unroll
        for (int it = 0; it < 3; ++it) {
            if (it < 2) {
                int d = (it + 1) * 256 + lane * 4;
#pragma unroll
                for (int k = 0; k < 8; ++k)
                    nxt[k] = *(const float4*)(base + (size_t)k * SMAX * DIM + d);
            }
            int p = 0;
#pragma unroll
            for (int i = 0; i < 8; ++i)
#pragma unroll
                for (int j = i; j < 8; ++j) {
                    g[p] += cur[i].x * cur[j].x + cur[i].y * cur[j].y +
                            cur[i].z * cur[j].z + cur[i].w * cur[j].w;
                    ++p;
                }
            if (it < 2) {
#pragma unroll
                for (int k = 0; k < 8; ++k) cur[k] = nxt[k];
            }
        }
        // --- Phase B: wave reduce-to-all (DPP + 2 shuffles per value) ---
#pragma unroll
        for (int p = 0; p < 36; ++p) g[p] = wave_reduce_add(g[p]);

        // --- Phase C: start reload of chunk 0 (L2-hot), then chol under the latency ---
#pragma unroll
        for (int k = 0; k < 8; ++k)
            cur[k] = *(const float4*)(base + (size_t)k * SMAX * DIM + lane * 4);

        // Reference window tables: left only when k >= WS(=2); right = k+1..min(k+2,7); k last.
        static constexpr int IDX0[5] = {1, 2, 0, 0, 0};
        static constexpr int IDX1[5] = {2, 3, 1, 0, 0};
        static constexpr int IDX2[5] = {0, 1, 3, 4, 2};
        static constexpr int IDX3[5] = {1, 2, 4, 5, 3};
        static constexpr int IDX4[5] = {2, 3, 5, 6, 4};
        static constexpr int IDX5[5] = {3, 4, 6, 7, 5};
        static constexpr int IDX6[5] = {4, 5, 7, 6, 0};
        static constexpr int IDX7[5] = {5, 6, 7, 0, 0};
        float a[8], n[8];
        alpha_nov<3>(g, IDX0, a[0], n[0]);
        alpha_nov<3>(g, IDX1, a[1], n[1]);
        alpha_nov<5>(g, IDX2, a[2], n[2]);
        alpha_nov<5>(g, IDX3, a[3], n[3]);
        alpha_nov<5>(g, IDX4, a[4], n[4]);
        alpha_nov<5>(g, IDX5, a[5], n[5]);
        alpha_nov<4>(g, IDX6, a[6], n[6]);
        alpha_nov<3>(g, IDX7, a[7], n[7]);
        float sa = 0.0f, sn = 0.0f;
#pragma unroll
        for (int k = 0; k < 8; ++k) { sa += a[k]; sn += n[k]; }
        float isa = frcp(sa), isn = frcp(sn);
        float al[8], ss = 0.0f;
#pragma unroll
        for (int k = 0; k < 8; ++k) { al[k] = a[k] * isa + n[k] * isn; ss += al[k]; }
        float iss = frcp(ss);
        // token variance (consecutive-layer cosine sims)
        float c[7], mu = 0.0f;
#pragma unroll
        for (int i = 0; i < 7; ++i) {
            float denom = g[gp(i, i)] * g[gp(i + 1, i + 1)];
            c[i] = g[gp(i, i + 1)] * frsq(denom > 1e-16f ? denom : 1e-16f);
            mu += c[i];
        }
        mu *= (1.0f / 7.0f);
        float var = 0.0f;
#pragma unroll
        for (int i = 0; i < 7; ++i) var += (c[i] - mu) * (c[i] - mu);
        float vraw = var * (1.0f / 6.0f);  // ddof=1
        vloc = vraw;
        float p8[8];
#pragma unroll
        for (int k = 0; k < 8; ++k) p8[k] = al[k] * iss * vraw;

        // --- Phase D: weighted accumulate, chunks pipelined, reads hit L2 ---
#pragma unroll
        for (int it = 0; it < 3; ++it) {
            if (it < 2) {
                int d = (it + 1) * 256 + lane * 4;
#pragma unroll
                for (int k = 0; k < 8; ++k)
                    nxt[k] = *(const float4*)(base + (size_t)k * SMAX * DIM + d);
            }
#pragma unroll
            for (int k = 0; k < 8; ++k) {
                acc12[it].x += p8[k] * cur[k].x;
                acc12[it].y += p8[k] * cur[k].y;
                acc12[it].z += p8[k] * cur[k].z;
                acc12[it].w += p8[k] * cur[k].w;
            }
            if (it < 2) {
#pragma unroll
                for (int k = 0; k < 8; ++k) cur[k] = nxt[k];
            }
        }

        // --- Phase E: block-level reduce into LDS ---
#pragma unroll
        for (int it = 0; it < 3; ++it) {
            int d = it * 256 + lane * 4;
            atomicAdd(&part[d + 0], acc12[it].x);
            atomicAdd(&part[d + 1], acc12[it].y);
            atomicAdd(&part[d + 2], acc12[it].z);
            atomicAdd(&part[d + 3], acc12[it].w);
        }
        if (lane == 0) atomicAdd(&vpart, vloc);
    }
    __syncthreads();

    float* pd = P + ((size_t)b * NSEG + seg) * DIM;
    for (int i = threadIdx.x; i < DIM; i += 256) pd[i] = part[i];
    if (threadIdx.x == 0) Vp[b * NSEG + seg] = vpart;
}

// ---------------- final reduce: out[b,d] = sum_seg P / sum_seg Vp ----------------
__global__ void k_reduce(const float* __restrict__ P, const float* __restrict__ Vp,
                         float* __restrict__ out) {
    int b = blockIdx.x;
    int d = threadIdx.x;  // 768 threads
    __shared__ float vred[NSEG];
    __shared__ float vinv;
    if (d < NSEG) vred[d] = Vp[b * NSEG + d];
    __syncthreads();
    if (d == 0) {
        float s = 0.0f;
        for (int i = 0; i < NSEG; ++i) s += vred[i];
        vinv = 1.0f / s;
    }
    __syncthreads();
    float s = 0.0f;
    const float* pb = P + (size_t)b * NSEG * DIM;
    for (int seg = 0; seg < NSEG; ++seg) s += pb[(size_t)seg * DIM + d];
    out[b * DIM + d] = s * vinv;
}

extern "C" void kernel_launch(void* const* d_in, const int* in_sizes, int n_in,
                              void* d_out, int out_size, void* d_ws, size_t ws_size,
                              hipStream_t stream) {
    const float* hs = (const float*)d_in[0];   // (8, 12, 512, 768) f32
    const int* mask = (const int*)d_in[1];     // (8, 512) i32
    float* out = (float*)d_out;                // (8, 768) f32
    char* ws = (char*)d_ws;
    // ws layout: [0] int T | [256] P 8*NSEG*768 f | Vp 8*NSEG f
    int* wsT = (int*)ws;
    float* P = (float*)(ws + 256);
    float* Vp = (float*)(ws + 256 + (size_t)8 * NSEG * DIM * 4);

    k_init<<<1, 512, 0, stream>>>(mask, wsT);
    k_main<<<dim3(NSEG, 8), 256, 0, stream>>>(hs, wsT, P, Vp);
    k_reduce<<<8, DIM, 0, stream>>>(P, Vp, out);
}